// Round 9
// baseline (659.551 us; speedup 1.0000x reference)
//
#include <hip/hip_runtime.h>
#include <cstdint>
#include <cstddef>

#define B_  2
#define S_  2048
#define D_  4096
#define NH  32
#define NKV 8
#define HD  128

typedef unsigned short u16;
typedef unsigned int   u32;
typedef __attribute__((ext_vector_type(8))) short short8;
typedef __attribute__((ext_vector_type(4))) float f32x4;
typedef __attribute__((ext_vector_type(4))) u32   u32x4;

__device__ __forceinline__ u16 f2bf(float f) {
  u32 u = __float_as_uint(f);
  u32 r = (u + 0x7FFFu + ((u >> 16) & 1u)) >> 16;  // RNE
  return (u16)r;
}
__device__ __forceinline__ float bf2f(u32 lo16) {
  return __uint_as_float(lo16 << 16);
}
__device__ __forceinline__ u32 cvtpk_bf16(float lo, float hi) {
  u32 r;
  asm("v_cvt_pk_bf16_f32 %0, %1, %2" : "=v"(r) : "v"(lo), "v"(hi));
  return r;
}
__device__ __forceinline__ short8 u32x4_to_short8(u32x4 v) {
  union { u32x4 a; short8 b; } u; u.a = v; return u.b;
}
__device__ __forceinline__ void load_lds16(const void* g, void* lds) {
  __builtin_amdgcn_global_load_lds(
      (const __attribute__((address_space(1))) u32*)g,
      (__attribute__((address_space(3))) u32*)lds, 16, 0, 0);
}

// ---------------- fused fp32 -> bf16 converter for all 5 tensors ----------------
__global__ __launch_bounds__(256) void cvt_all(
    const float* __restrict__ x, const float* __restrict__ wq,
    const float* __restrict__ wk, const float* __restrict__ wv,
    const float* __restrict__ wo, u16* __restrict__ Xb, u16* __restrict__ Wqb,
    u16* __restrict__ Wkb, u16* __restrict__ Wvb, u16* __restrict__ Wob) {
  long i = (long)blockIdx.x * 256 + threadIdx.x;
  const float* src; u16* dst; long off;
  if (i < 2097152L)      { src = x;  dst = Xb;  off = i; }
  else if (i < 4194304L) { src = wq; dst = Wqb; off = i - 2097152L; }
  else if (i < 4718592L) { src = wk; dst = Wkb; off = i - 4194304L; }
  else if (i < 5242880L) { src = wv; dst = Wvb; off = i - 4718592L; }
  else                   { src = wo; dst = Wob; off = i - 5242880L; }
  const float4* s = (const float4*)src + off * 2;
  float4 a = s[0], b = s[1];
  uint4 o;
  o.x = (u32)f2bf(a.x) | ((u32)f2bf(a.y) << 16);
  o.y = (u32)f2bf(a.z) | ((u32)f2bf(a.w) << 16);
  o.z = (u32)f2bf(b.x) | ((u32)f2bf(b.y) << 16);
  o.w = (u32)f2bf(b.z) | ((u32)f2bf(b.w) << 16);
  *((uint4*)dst + off) = o;
}

// ================= 256^2 tile, 8-phase GEMM with one-phase-ahead reg prefetch ====
// Each phase: {stage 1 half-tile | mid-BAR | MFMA (operands read LAST phase) |
// [vmcnt wait at ph4/ph8] | ds_read NEXT phase's operands | end-BAR}.
// LDS drain of phase p+1's operands overlaps phase p's MFMA drain.
// WAR safety: every region's prefetch-read completes before its consuming phase's
// end-barrier (lgkm before MFMA), and the overwriting stage issues >= 1 full
// barrier-separated phase later. vmcnt ledger: 14 outstanding at ph4/ph8 waits,
// vmcnt(6) drains exactly the tile whose operands are then read.
template <int MODE, bool ROPE>
__global__ __launch_bounds__(512, 2)
void gemm256(const u16* __restrict__ A, const u16* __restrict__ Bw,
             void* __restrict__ Cout, int M, int N, int K, int Hh,
             const float* __restrict__ fc, const float* __restrict__ fs) {
  const int tid = threadIdx.x, lid = tid & 63, w = tid >> 6;
  const int lr = lid & 15, lg = lid >> 4;
  const int wm = w >> 2, wn = w & 3;

  // chunked XCD swizzle for the 16x16 grid
  int lin = blockIdx.y * gridDim.x + blockIdx.x;
  int bm, bn;
  if (gridDim.x == 16 && gridDim.y == 16) {
    int xcd = lin & 7, idx = lin >> 3;
    bm = ((xcd & 3) * 4 + (idx >> 3)) * 256;
    bn = ((xcd >> 2) * 8 + (idx & 7)) * 256;
  } else {
    bm = blockIdx.y * 256;
    bn = blockIdx.x * 256;
  }

  __shared__ __align__(16) u16 Al[2][2][128 * 64];
  __shared__ __align__(16) u16 Bl[2][2][128 * 64];

  f32x4 acc[8][4];
#pragma unroll
  for (int i = 0; i < 8; ++i)
#pragma unroll
    for (int j = 0; j < 4; ++j) acc[i][j] = (f32x4){0.f, 0.f, 0.f, 0.f};

#define STG_AQ(BUF, QH, KT)                                                    \
  do {                                                                         \
    _Pragma("unroll")                                                          \
    for (int j_ = 0; j_ < 2; ++j_) {                                           \
      int c_ = j_ * 512 + tid;                                                 \
      int idx_ = c_ >> 3, cb_ = c_ & 7;                                        \
      int sr_ = bm + ((idx_ & 64) << 1) + (QH) * 64 + (idx_ & 63);             \
      int sc_ = (cb_ ^ idx_) & 7;                                              \
      load_lds16(A + (size_t)sr_ * K + (KT) + sc_ * 8, &Al[BUF][QH][c_ * 8]);  \
    }                                                                          \
  } while (0)
#define STG_BN(BUF, NHh, KT)                                                   \
  do {                                                                         \
    _Pragma("unroll")                                                          \
    for (int j_ = 0; j_ < 2; ++j_) {                                           \
      int c_ = j_ * 512 + tid;                                                 \
      int idx_ = c_ >> 3, cb_ = c_ & 7;                                        \
      int sr_ = bn + ((idx_ & 96) << 1) + (NHh) * 32 + (idx_ & 31);            \
      int sc_ = (cb_ ^ idx_) & 7;                                              \
      load_lds16(Bw + (size_t)sr_ * K + (KT) + sc_ * 8, &Bl[BUF][NHh][c_ * 8]);\
    }                                                                          \
  } while (0)
#define READ_AQ(BUF, MH, DST)                                                  \
  do {                                                                         \
    _Pragma("unroll")                                                          \
    for (int mi_ = 0; mi_ < 4; ++mi_) {                                        \
      int ix_ = wm * 64 + mi_ * 16 + lr;                                       \
      _Pragma("unroll")                                                        \
      for (int ks_ = 0; ks_ < 2; ++ks_)                                        \
        DST[mi_][ks_] = *(const short8*)&Al[BUF][MH]                           \
            [ix_ * 64 + (((ks_ * 4 + lg) ^ ix_) & 7) * 8];                     \
    }                                                                          \
  } while (0)
#define READ_BN(BUF, NHh, DST)                                                 \
  do {                                                                         \
    _Pragma("unroll")                                                          \
    for (int ni_ = 0; ni_ < 2; ++ni_) {                                        \
      int ix_ = wn * 32 + ni_ * 16 + lr;                                       \
      _Pragma("unroll")                                                        \
      for (int ks_ = 0; ks_ < 2; ++ks_)                                        \
        DST[ni_][ks_] = *(const short8*)&Bl[BUF][NHh]                          \
            [ix_ * 64 + (((ks_ * 4 + lg) ^ ix_) & 7) * 8];                     \
    }                                                                          \
  } while (0)
#define MFMA16(AARR, BARR, MH, NHh)                                            \
  do {                                                                         \
    __builtin_amdgcn_s_setprio(1);                                             \
    _Pragma("unroll")                                                          \
    for (int ks_ = 0; ks_ < 2; ++ks_)                                          \
      _Pragma("unroll")                                                        \
      for (int mi_ = 0; mi_ < 4; ++mi_)                                        \
        _Pragma("unroll")                                                      \
        for (int ni_ = 0; ni_ < 2; ++ni_)                                      \
          acc[(MH) * 4 + mi_][(NHh) * 2 + ni_] =                               \
              __builtin_amdgcn_mfma_f32_16x16x32_bf16(                         \
                  AARR[mi_][ks_], BARR[ni_][ks_],                              \
                  acc[(MH) * 4 + mi_][(NHh) * 2 + ni_], 0, 0, 0);              \
    __builtin_amdgcn_s_setprio(0);                                             \
  } while (0)
#define BAR() __builtin_amdgcn_s_barrier()

  const int nt = K >> 6;        // 64 K-tiles (even)
  const int niter = nt >> 1;

  short8 aqA[4][2], aqB[4][2], bn0[2][2], bn1[2][2];

  // prologue: T0 complete + T1 {Aq0,Bn0,Bn1}; then pre-read ph1 operands
  STG_AQ(0, 0, 0); STG_BN(0, 0, 0); STG_BN(0, 1, 0); STG_AQ(0, 1, 0);
  STG_AQ(1, 0, 64); STG_BN(1, 0, 64); STG_BN(1, 1, 64);
  asm volatile("s_waitcnt vmcnt(6)" ::: "memory");  // T0's 8 loads landed
  BAR();
  READ_AQ(0, 0, aqA); READ_BN(0, 0, bn0);

  for (int j = 0; j < niter; ++j) {
    const bool pf = (j + 1 < niter);
    const int k1 = (2 * j + 1) << 6, k2 = (2 * j + 2) << 6, k3 = (2 * j + 3) << 6;

    // ---- ph1: T0 m0n0; stage A(2j+1)-q1; prefetch B0-n1
    STG_AQ(1, 1, k1);
    BAR();
    MFMA16(aqA, bn0, 0, 0);
    READ_BN(0, 1, bn1);
    BAR();

    // ---- ph2: T0 m0n1; stage A(2j+2)-q0; prefetch A0-m1
    if (pf) STG_AQ(0, 0, k2);
    BAR();
    MFMA16(aqA, bn1, 0, 1);
    READ_AQ(0, 1, aqB);
    BAR();

    // ---- ph3: T0 m1n0; stage B(2j+2)-n0
    if (pf) STG_BN(0, 0, k2);
    BAR();
    MFMA16(aqB, bn0, 1, 0);
    BAR();

    // ---- ph4: T0 m1n1; stage B(2j+2)-n1; WAIT T1 landed; prefetch T1 m0,n0
    if (pf) STG_BN(0, 1, k2);
    BAR();
    MFMA16(aqB, bn1, 1, 1);
    if (pf) asm volatile("s_waitcnt vmcnt(6)" ::: "memory");
    else    asm volatile("s_waitcnt vmcnt(0)" ::: "memory");
    READ_AQ(1, 0, aqA); READ_BN(1, 0, bn0);
    BAR();

    // ---- ph5: T1 m0n0; stage A(2j+2)-q1; prefetch B1-n1
    if (pf) STG_AQ(0, 1, k2);
    BAR();
    MFMA16(aqA, bn0, 0, 0);
    READ_BN(1, 1, bn1);
    BAR();

    // ---- ph6: T1 m0n1; stage A(2j+3)-q0; prefetch A1-m1
    if (pf) STG_AQ(1, 0, k3);
    BAR();
    MFMA16(aqA, bn1, 0, 1);
    READ_AQ(1, 1, aqB);
    BAR();

    // ---- ph7: T1 m1n0; stage B(2j+3)-n0
    if (pf) STG_BN(1, 0, k3);
    BAR();
    MFMA16(aqB, bn0, 1, 0);
    BAR();

    // ---- ph8: T1 m1n1; stage B(2j+3)-n1; WAIT tile 2j+2 landed; prefetch it
    if (pf) STG_BN(1, 1, k3);
    BAR();
    MFMA16(aqB, bn1, 1, 1);
    if (pf) {
      asm volatile("s_waitcnt vmcnt(6)" ::: "memory");
      READ_AQ(0, 0, aqA); READ_BN(0, 0, bn0);
    }
    BAR();
  }
#undef STG_AQ
#undef STG_BN
#undef READ_AQ
#undef READ_BN
#undef MFMA16
#undef BAR

  // ---- epilogue
#pragma unroll
  for (int mi = 0; mi < 8; ++mi)
#pragma unroll
    for (int ni = 0; ni < 4; ++ni)
#pragma unroll
      for (int v = 0; v < 4; ++v) {
        int m = bm + wm * 128 + mi * 16 + lg * 4 + v;
        int n = bn + wn * 64 + ni * 16 + lr;
        float val = acc[mi][ni][v];
        if (ROPE) {
          int srow = m & (S_ - 1);
          int j = (n & (HD - 1)) >> 1;
          float c = fc[(size_t)srow * 64 + j];
          float s = fs[(size_t)srow * 64 + j];
          float partner = __shfl_xor(val, 1);
          val = (n & 1) ? (val * c + partner * s) : (val * c - partner * s);
          val *= (0.08838834764831845f * 1.44269504088896340f);  // attn scale (log2)
        }
        if (MODE == 0) {
          ((float*)Cout)[(size_t)m * N + n] = val;
        } else if (MODE == 1) {
          int b = m >> 11, s = m & (S_ - 1), hh = n >> 7, d = n & (HD - 1);
          ((u16*)Cout)[(((size_t)(b * Hh + hh)) * S_ + s) * HD + d] = f2bf(val);
        } else {
          int b = m >> 11, s = m & (S_ - 1), hh = n >> 7, d = n & (HD - 1);
          ((u16*)Cout)[(((size_t)(b * Hh + hh)) * HD + d) * S_ + s] = f2bf(val);
        }
      }
}

// ---------------- merged K+V projection (128^2 2-phase), blockIdx.z selects ----
__global__ __launch_bounds__(256)
void gemm_kv(const u16* __restrict__ Xb, const u16* __restrict__ Wk,
             const u16* __restrict__ Wv, u16* __restrict__ Kr, u16* __restrict__ Vt,
             const float* __restrict__ fc, const float* __restrict__ fs) {
  const int tid = threadIdx.x;
  const int lid = tid & 63, w = tid >> 6;
  const int lr = lid & 15, lg = lid >> 4;
  const int wm = w >> 1, wn = w & 1;
  const int zz = blockIdx.z;
  const u16* Bw = zz ? Wv : Wk;
  const int K = D_;

  const int gx = gridDim.x;
  const int nwg = gx * gridDim.y;
  const int lin = blockIdx.y * gx + blockIdx.x;
  const int cpx = nwg >> 3;
  const int lin2 = (lin & 7) * cpx + (lin >> 3);
  const int bm = (lin2 / gx) * 128, bn = (lin2 % gx) * 128;

  __shared__ __align__(16) u16 Al[128 * 64];
  __shared__ __align__(16) u16 Bl[128 * 64];
  f32x4 acc[4][4];
#pragma unroll
  for (int i = 0; i < 4; ++i)
#pragma unroll
    for (int j = 0; j < 4; ++j) acc[i][j] = (f32x4){0.f, 0.f, 0.f, 0.f};

  for (int k0 = 0; k0 < K; k0 += 64) {
    __syncthreads();
#pragma unroll
    for (int i = 0; i < 4; ++i) {
      int c = i * 256 + tid;
      int row = c >> 3, cb = c & 7;
      int cbs = (cb ^ row) & 7;
      load_lds16(Xb + (size_t)(bm + row) * K + k0 + cbs * 8, &Al[c * 8]);
    }
#pragma unroll
    for (int i = 0; i < 4; ++i) {
      int c = i * 256 + tid;
      int row = c >> 3, cb = c & 7;
      int cbs = (cb ^ row) & 7;
      load_lds16(Bw + (size_t)(bn + row) * K + k0 + cbs * 8, &Bl[c * 8]);
    }
    __syncthreads();
#pragma unroll
    for (int ks = 0; ks < 2; ++ks) {
      short8 af[4], bf[4];
#pragma unroll
      for (int mi = 0; mi < 4; ++mi) {
        int row = wm * 64 + mi * 16 + lr;
        af[mi] = *(const short8*)&Al[row * 64 + (((ks * 4 + lg) ^ row) & 7) * 8];
      }
#pragma unroll
      for (int ni = 0; ni < 4; ++ni) {
        int row = wn * 64 + ni * 16 + lr;
        bf[ni] = *(const short8*)&Bl[row * 64 + (((ks * 4 + lg) ^ row) & 7) * 8];
      }
#pragma unroll
      for (int mi = 0; mi < 4; ++mi)
#pragma unroll
        for (int ni = 0; ni < 4; ++ni)
          acc[mi][ni] = __builtin_amdgcn_mfma_f32_16x16x32_bf16(af[mi], bf[ni], acc[mi][ni], 0, 0, 0);
    }
  }
#pragma unroll
  for (int mi = 0; mi < 4; ++mi)
#pragma unroll
    for (int ni = 0; ni < 4; ++ni)
#pragma unroll
      for (int v = 0; v < 4; ++v) {
        int m = bm + wm * 64 + mi * 16 + lg * 4 + v;
        int n = bn + wn * 64 + ni * 16 + lr;
        float val = acc[mi][ni][v];
        int b = m >> 11, s = m & (S_ - 1), hh = n >> 7, d = n & (HD - 1);
        if (zz == 0) {
          int j = d >> 1;
          float c = fc[(size_t)s * 64 + j];
          float sn = fs[(size_t)s * 64 + j];
          float partner = __shfl_xor(val, 1);
          val = (n & 1) ? (val * c + partner * sn) : (val * c - partner * sn);
          Kr[(((size_t)(b * NKV + hh)) * S_ + s) * HD + d] = f2bf(val);
        } else {
          int x = s & 31;
          int sp = (s & ~31) | (((x >> 2) & 3) * 8 + ((x >> 4) & 1) * 4 + (x & 3));
          Vt[(((size_t)(b * NKV + hh)) * HD + d) * S_ + sp] = f2bf(val);
        }
      }
}

// ---------------- Flash attention, swapped-QK + zero-shuffle PV ----------------
__global__ __launch_bounds__(512, 4)
void attn_k(const u16* __restrict__ Qr, const u16* __restrict__ Kr,
            const u16* __restrict__ Vt, u16* __restrict__ Ao) {
  const int xp = blockIdx.x, h = blockIdx.y, b = blockIdx.z;
  const int kvh = h >> 2;
  const int tid = threadIdx.x, lid = tid & 63, w = tid >> 6;
  const int lr = lid & 15, lg = lid >> 4;
  __shared__ __align__(16) u16 Kl[2][64 * 128];
  __shared__ __align__(16) u16 Vl[2][128 * 64];

  const size_t qbase = ((size_t)(b * NH + h)) * S_ * HD;
  const size_t kbase = ((size_t)(b * NKV + kvh)) * S_ * HD;
  const size_t vbase = ((size_t)(b * NKV + kvh)) * HD * S_;

#define STAGE(BUF, KT)                                                              \
  do {                                                                              \
    _Pragma("unroll")                                                               \
    for (int i_ = 0; i_ < 2; ++i_) {                                                \
      int c_ = i_ * 512 + tid;                                                      \
      int row_ = c_ >> 4, cb_ = c_ & 15;                                            \
      int cbs_ = (cb_ & 8) | ((cb_ ^ row_) & 7);                                    \
      load_lds16(&Kr[kbase + (size_t)((KT) + row_) * HD + cbs_ * 8],                \
                 &Kl[BUF][(i_ * 512 + w * 64) * 8]);                                \
    }                                                                               \
    _Pragma("unroll")                                                               \
    for (int i_ = 0; i_ < 2; ++i_) {                                                \
      int c_ = i_ * 512 + tid;                                                      \
      int d_ = c_ >> 3, cb_ = c_ & 7;                                               \
      int cbs_ = (cb_ ^ d_) & 7;                                                    \
      load_lds16(&Vt[vbase + (size_t)d_ * S_ + (KT) + cbs_ * 8],                    \
                 &Vl[BUF][(i_ * 512 + w * 64) * 8]);                                \
    }                                                                               \
  } while (0)

  for (int part = 0; part < 2; ++part) {
    const int qi = part ? xp : (15 - xp);
    const int qb = qi * 128;
    const int ntiles = qi * 2 + 2;
    const int q_abs = qb + w * 16 + lr;

    short8 qf[4];
#pragma unroll
    for (int ks = 0; ks < 4; ++ks)
      qf[ks] = *(const short8*)&Qr[qbase + (size_t)q_abs * HD + ks * 32 + lg * 8];

    float m2 = -3.0e38f, osum = 0.f;
    f32x4 oacc[8];
#pragma unroll
    for (int nd = 0; nd < 8; ++nd) oacc[nd] = (f32x4){0.f, 0.f, 0.f, 0.f};

    STAGE(0, 0);
    __syncthreads();
    int cur = 0;

    for (int t = 0; t < ntiles; ++t) {
      const int kt = t * 64;
      if (t + 1 < ntiles) STAGE(cur ^ 1, kt + 64);

      f32x4 sc[4];
#pragma unroll
      for (int ni = 0; ni < 4; ++ni) sc[ni] = (f32x4){0.f, 0.f, 0.f, 0.f};
      __builtin_amdgcn_s_setprio(1);
#pragma unroll
      for (int ks = 0; ks < 4; ++ks) {
#pragma unroll
        for (int ni = 0; ni < 4; ++ni) {
          int row = ni * 16 + lr;
          int ch = ks * 4 + lg;
          int chs = (ch & 8) | ((ch ^ row) & 7);
          short8 kf = *(const short8*)&Kl[cur][row * 128 + chs * 8];
          sc[ni] = __builtin_amdgcn_mfma_f32_16x16x32_bf16(kf, qf[ks], sc[ni], 0, 0, 0);
        }
      }
      __builtin_amdgcn_s_setprio(0);

      const bool edge = (kt + 64 > qb);
      if (edge) {
#pragma unroll
        for (int ni = 0; ni < 4; ++ni)
#pragma unroll
          for (int v = 0; v < 4; ++v) {
            int kv = kt + ni * 16 + lg * 4 + v;
            if (kv > q_abs) sc[ni][v] = -3.0e38f;
          }
      }
      float mab = fmaxf(fmaxf(fmaxf(sc[0][0], sc[0][1]), fmaxf(sc[0][2], sc[0][3])),
                        fmaxf(fmaxf(sc[1][0], sc[1][1]), fmaxf(sc[1][2], sc[1][3])));
      float mcd = fmaxf(fmaxf(fmaxf(sc[2][0], sc[2][1]), fmaxf(sc[2][2], sc[2][3])),
                        fmaxf(fmaxf(sc[3][0], sc[3][1]), fmaxf(sc[3][2], sc[3][3])));
      float mx = fmaxf(mab, mcd);
      mx = fmaxf(mx, __shfl_xor(mx, 16));
      mx = fmaxf(mx, __shfl_xor(mx, 32));

      if (__any(mx > m2 + 8.0f)) {
        float mnew = fmaxf(m2, mx);
        float fr = exp2f(m2 - mnew);
        m2 = mnew;
        osum *= fr;
#pragma unroll
        for (int nd = 0; nd < 8; ++nd) oacc[nd] *= fr;
      }

      u32x4 pw0, pw1;
      float ps = 0.f;
#pragma unroll
      for (int ni = 0; ni < 4; ++ni) {
#pragma unroll
        for (int p = 0; p < 2; ++p) {
          float e0 = exp2f(sc[ni][2 * p] - m2);
          float e1 = exp2f(sc[ni][2 * p + 1] - m2);
          ps += e0 + e1;
          u32 pk = cvtpk_bf16(e0, e1);
          if (ni < 2) pw0[(ni & 1) * 2 + p] = pk;
          else        pw1[(ni & 1) * 2 + p] = pk;
        }
      }
      osum += ps;
      const short8 pf0 = u32x4_to_short8(pw0);
      const short8 pf1 = u32x4_to_short8(pw1);

      __builtin_amdgcn_s_setprio(1);
#pragma unroll
      for (int ks = 0; ks < 2; ++ks) {
        const short8 pfk = ks ? pf1 : pf0;
#pragma unroll
        for (int nd = 0; nd < 8; ++nd) {
          int rowv = nd * 16 + lr;
          int ch = ks * 4 + lg;
          short8 vf = *(const short8*)&Vl[cur][rowv * 64 + ((ch ^ rowv) & 7) * 8];
          oacc[nd] = __builtin_amdgcn_mfma_f32_16x16x32_bf16(vf, pfk, oacc[nd], 0, 0, 0);
        }
      }
      __builtin_amdgcn_s_setprio(0);
      __syncthreads();
      cur ^= 1;
    }

    float os = osum;
    os += __shfl_xor(os, 16);
    os += __shfl_xor(os, 32);
    const float inv = 1.0f / os;
    const size_t orow = ((size_t)(b * S_ + q_abs)) * D_ + h * HD;
    u32* AoW = (u32*)Ao;
#pragma unroll
    for (int nd = 0; nd < 8; ++nd) {
#pragma unroll
      for (int p = 0; p < 2; ++p) {
        u32 pk = cvtpk_bf16(oacc[nd][2 * p] * inv, oacc[nd][2 * p + 1] * inv);
        AoW[(orow + nd * 16 + lg * 4 + 2 * p) >> 1] = pk;
      }
    }
  }
#undef STAGE
}

// ---------------- host launch ----------------
extern "C" void kernel_launch(void* const* d_in, const int* in_sizes, int n_in,
                              void* d_out, int out_size, void* d_ws, size_t ws_size,
                              hipStream_t stream) {
  const float* x  = (const float*)d_in[0];
  const float* wq = (const float*)d_in[1];
  const float* wk = (const float*)d_in[2];
  const float* wv = (const float*)d_in[3];
  const float* wo = (const float*)d_in[4];
  const float* fc = (const float*)d_in[5];
  const float* fs = (const float*)d_in[6];

  const size_t SZ_X  = (size_t)B_ * S_ * D_ * 2;
  const size_t SZ_WQ = (size_t)D_ * D_ * 2;
  const size_t SZ_WK = (size_t)NKV * HD * D_ * 2;
  char* ws = (char*)d_ws;
  u16* Xb  = (u16*)(ws);
  u16* Wqb = (u16*)(ws + SZ_X);
  u16* Wkb = (u16*)(ws + SZ_X + SZ_WQ);
  u16* Wvb = (u16*)(ws + SZ_X + SZ_WQ + SZ_WK);
  u16* Wob = (u16*)(ws + SZ_X + SZ_WQ + 2 * SZ_WK);
  u16* Qr  = (u16*)(ws + SZ_X + 2 * SZ_WQ + 2 * SZ_WK);
  u16* Kr  = (u16*)(ws + 2 * SZ_X + 2 * SZ_WQ + 2 * SZ_WK);
  u16* Vt  = (u16*)(ws + 2 * SZ_X + 2 * SZ_WQ + 3 * SZ_WK);
  u16* Ao  = (u16*)(ws + 2 * SZ_X + 2 * SZ_WQ + 4 * SZ_WK);
  const size_t NEEDED = 3 * SZ_X + 2 * SZ_WQ + 4 * SZ_WK;
  if (ws_size < NEEDED) return;

  cvt_all<<<28672, 256, 0, stream>>>(x, wq, wk, wv, wo, Xb, Wqb, Wkb, Wvb, Wob);

  gemm256<1, true><<<dim3(16, 16), 512, 0, stream>>>(
      Xb, Wqb, Qr, B_ * S_, D_, D_, NH, fc, fs);
  gemm_kv<<<dim3(8, 32, 2), 256, 0, stream>>>(Xb, Wkb, Wvb, Kr, Vt, fc, fs);

  attn_k<<<dim3(8, NH, B_), 512, 0, stream>>>(Qr, Kr, Vt, Ao);

  gemm256<0, false><<<dim3(16, 16), 512, 0, stream>>>(
      Ao, Wob, d_out, B_ * S_, D_, D_, 0, nullptr, nullptr);
}

// Round 10
// 498.273 us; speedup vs baseline: 1.3237x; 1.3237x over previous
//
#include <hip/hip_runtime.h>
#include <cstdint>
#include <cstddef>

#define B_  2
#define S_  2048
#define D_  4096
#define NH  32
#define NKV 8
#define HD  128

typedef unsigned short u16;
typedef unsigned int   u32;
typedef __attribute__((ext_vector_type(8))) short short8;
typedef __attribute__((ext_vector_type(4))) float f32x4;
typedef __attribute__((ext_vector_type(4))) u32   u32x4;

__device__ __forceinline__ u16 f2bf(float f) {
  u32 u = __float_as_uint(f);
  u32 r = (u + 0x7FFFu + ((u >> 16) & 1u)) >> 16;  // RNE
  return (u16)r;
}
__device__ __forceinline__ float bf2f(u32 lo16) {
  return __uint_as_float(lo16 << 16);
}
__device__ __forceinline__ u32 cvtpk_bf16(float lo, float hi) {
  u32 r;
  asm("v_cvt_pk_bf16_f32 %0, %1, %2" : "=v"(r) : "v"(lo), "v"(hi));
  return r;
}
__device__ __forceinline__ short8 u32x4_to_short8(u32x4 v) {
  union { u32x4 a; short8 b; } u; u.a = v; return u.b;
}
__device__ __forceinline__ void load_lds16(const void* g, void* lds) {
  __builtin_amdgcn_global_load_lds(
      (const __attribute__((address_space(1))) u32*)g,
      (__attribute__((address_space(3))) u32*)lds, 16, 0, 0);
}

// ---------------- fused fp32 -> bf16 converter for all 5 tensors ----------------
__global__ __launch_bounds__(256) void cvt_all(
    const float* __restrict__ x, const float* __restrict__ wq,
    const float* __restrict__ wk, const float* __restrict__ wv,
    const float* __restrict__ wo, u16* __restrict__ Xb, u16* __restrict__ Wqb,
    u16* __restrict__ Wkb, u16* __restrict__ Wvb, u16* __restrict__ Wob) {
  long i = (long)blockIdx.x * 256 + threadIdx.x;
  const float* src; u16* dst; long off;
  if (i < 2097152L)      { src = x;  dst = Xb;  off = i; }
  else if (i < 4194304L) { src = wq; dst = Wqb; off = i - 2097152L; }
  else if (i < 4718592L) { src = wk; dst = Wkb; off = i - 4194304L; }
  else if (i < 5242880L) { src = wv; dst = Wvb; off = i - 4718592L; }
  else                   { src = wo; dst = Wob; off = i - 5242880L; }
  const float4* s = (const float4*)src + off * 2;
  float4 a = s[0], b = s[1];
  uint4 o;
  o.x = (u32)f2bf(a.x) | ((u32)f2bf(a.y) << 16);
  o.y = (u32)f2bf(a.z) | ((u32)f2bf(a.w) << 16);
  o.z = (u32)f2bf(b.x) | ((u32)f2bf(b.y) << 16);
  o.w = (u32)f2bf(b.z) | ((u32)f2bf(b.w) << 16);
  *((uint4*)dst + off) = o;
}

// ================= 256^2 tile, 8-phase / 2-K-tile counted-vmcnt GEMM =============
// r8 schedule + m201 pinning: per phase {ds_read + stage -> sched_barrier(0) ->
// s_barrier -> s_waitcnt lgkmcnt(0) -> sched_barrier(0) -> setprio MFMA -> barrier}.
// Reads issue BEFORE the barrier (latency hides under barrier arrival); MFMA
// starts after one bulk lgkm drain. vmcnt(6) only at ph4/ph8 (r8 ledger).
template <int MODE, bool ROPE>
__global__ __launch_bounds__(512, 2)
void gemm256(const u16* __restrict__ A, const u16* __restrict__ Bw,
             void* __restrict__ Cout, int M, int N, int K, int Hh,
             const float* __restrict__ fc, const float* __restrict__ fs) {
  const int tid = threadIdx.x, lid = tid & 63, w = tid >> 6;
  const int lr = lid & 15, lg = lid >> 4;
  const int wm = w >> 2, wn = w & 3;

  // chunked XCD swizzle for the 16x16 grid
  int lin = blockIdx.y * gridDim.x + blockIdx.x;
  int bm, bn;
  if (gridDim.x == 16 && gridDim.y == 16) {
    int xcd = lin & 7, idx = lin >> 3;
    bm = ((xcd & 3) * 4 + (idx >> 3)) * 256;
    bn = ((xcd >> 2) * 8 + (idx & 7)) * 256;
  } else {
    bm = blockIdx.y * 256;
    bn = blockIdx.x * 256;
  }

  __shared__ __align__(16) u16 Al[2][2][128 * 64];
  __shared__ __align__(16) u16 Bl[2][2][128 * 64];

  f32x4 acc[8][4];
#pragma unroll
  for (int i = 0; i < 8; ++i)
#pragma unroll
    for (int j = 0; j < 4; ++j) acc[i][j] = (f32x4){0.f, 0.f, 0.f, 0.f};

#define STG_AQ(BUF, QH, KT)                                                    \
  do {                                                                         \
    _Pragma("unroll")                                                          \
    for (int j_ = 0; j_ < 2; ++j_) {                                           \
      int c_ = j_ * 512 + tid;                                                 \
      int idx_ = c_ >> 3, cb_ = c_ & 7;                                        \
      int sr_ = bm + ((idx_ & 64) << 1) + (QH) * 64 + (idx_ & 63);             \
      int sc_ = (cb_ ^ idx_) & 7;                                              \
      load_lds16(A + (size_t)sr_ * K + (KT) + sc_ * 8, &Al[BUF][QH][c_ * 8]);  \
    }                                                                          \
  } while (0)
#define STG_BN(BUF, NHh, KT)                                                   \
  do {                                                                         \
    _Pragma("unroll")                                                          \
    for (int j_ = 0; j_ < 2; ++j_) {                                           \
      int c_ = j_ * 512 + tid;                                                 \
      int idx_ = c_ >> 3, cb_ = c_ & 7;                                        \
      int sr_ = bn + ((idx_ & 96) << 1) + (NHh) * 32 + (idx_ & 31);            \
      int sc_ = (cb_ ^ idx_) & 7;                                              \
      load_lds16(Bw + (size_t)sr_ * K + (KT) + sc_ * 8, &Bl[BUF][NHh][c_ * 8]);\
    }                                                                          \
  } while (0)
#define READ_AQ(BUF, MH)                                                       \
  do {                                                                         \
    _Pragma("unroll")                                                          \
    for (int mi_ = 0; mi_ < 4; ++mi_) {                                        \
      int ix_ = wm * 64 + mi_ * 16 + lr;                                       \
      _Pragma("unroll")                                                        \
      for (int ks_ = 0; ks_ < 2; ++ks_)                                        \
        aq[mi_][ks_] = *(const short8*)&Al[BUF][MH]                            \
            [ix_ * 64 + (((ks_ * 4 + lg) ^ ix_) & 7) * 8];                     \
    }                                                                          \
  } while (0)
#define READ_BN(BUF, NHh, ARR)                                                 \
  do {                                                                         \
    _Pragma("unroll")                                                          \
    for (int ni_ = 0; ni_ < 2; ++ni_) {                                        \
      int ix_ = wn * 32 + ni_ * 16 + lr;                                       \
      _Pragma("unroll")                                                        \
      for (int ks_ = 0; ks_ < 2; ++ks_)                                        \
        ARR[ni_][ks_] = *(const short8*)&Bl[BUF][NHh]                          \
            [ix_ * 64 + (((ks_ * 4 + lg) ^ ix_) & 7) * 8];                     \
    }                                                                          \
  } while (0)
#define MFMA16(MH, NHh, ARR)                                                   \
  do {                                                                         \
    __builtin_amdgcn_s_setprio(1);                                             \
    _Pragma("unroll")                                                          \
    for (int ks_ = 0; ks_ < 2; ++ks_)                                          \
      _Pragma("unroll")                                                        \
      for (int mi_ = 0; mi_ < 4; ++mi_)                                        \
        _Pragma("unroll")                                                      \
        for (int ni_ = 0; ni_ < 2; ++ni_)                                      \
          acc[(MH) * 4 + mi_][(NHh) * 2 + ni_] =                               \
              __builtin_amdgcn_mfma_f32_16x16x32_bf16(                         \
                  aq[mi_][ks_], ARR[ni_][ks_],                                 \
                  acc[(MH) * 4 + mi_][(NHh) * 2 + ni_], 0, 0, 0);              \
    __builtin_amdgcn_s_setprio(0);                                             \
  } while (0)
#define BAR()   __builtin_amdgcn_s_barrier()
#define SCHED0() __builtin_amdgcn_sched_barrier(0)
#define LGKM0() asm volatile("s_waitcnt lgkmcnt(0)" ::: "memory")

  const int nt = K >> 6;        // 64 K-tiles (even)
  const int niter = nt >> 1;    // 32 iterations x 2 K-tiles

  // prologue: T0 complete (4 half-tiles) + T1 minus its A-q1 (3 half-tiles)
  STG_AQ(0, 0, 0); STG_BN(0, 0, 0); STG_BN(0, 1, 0); STG_AQ(0, 1, 0);
  STG_AQ(1, 0, 64); STG_BN(1, 0, 64); STG_BN(1, 1, 64);
  asm volatile("s_waitcnt vmcnt(6)" ::: "memory");  // T0's 8 loads landed
  BAR();

  short8 aq[4][2], bn0[2][2], bn1[2][2];
  for (int j = 0; j < niter; ++j) {
    const bool pf = (j + 1 < niter);
    const int k1 = (2 * j + 1) << 6, k2 = (2 * j + 2) << 6, k3 = (2 * j + 3) << 6;

    // ---- ph1: T0 m0n0; stage A(2j+1)-q1
    READ_AQ(0, 0); READ_BN(0, 0, bn0);
    STG_AQ(1, 1, k1);
    SCHED0(); BAR(); LGKM0(); SCHED0();
    MFMA16(0, 0, bn0); BAR();

    // ---- ph2: T0 m0n1; stage A(2j+2)-q0
    READ_BN(0, 1, bn1);
    if (pf) STG_AQ(0, 0, k2);
    SCHED0(); BAR(); LGKM0(); SCHED0();
    MFMA16(0, 1, bn1); BAR();

    // ---- ph3: T0 m1n0; stage B(2j+2)-n0
    READ_AQ(0, 1);
    if (pf) STG_BN(0, 0, k2);
    SCHED0(); BAR(); LGKM0(); SCHED0();
    MFMA16(1, 0, bn0); BAR();

    // ---- ph4: T0 m1n1; stage B(2j+2)-n1; WAIT (T1 ready)
    if (pf) STG_BN(0, 1, k2);
    SCHED0(); BAR(); LGKM0(); SCHED0();
    MFMA16(1, 1, bn1);
    if (pf) asm volatile("s_waitcnt vmcnt(6)" ::: "memory");
    else    asm volatile("s_waitcnt vmcnt(0)" ::: "memory");
    BAR();

    // ---- ph5: T1 m0n0; stage A(2j+2)-q1
    READ_AQ(1, 0); READ_BN(1, 0, bn0);
    if (pf) STG_AQ(0, 1, k2);
    SCHED0(); BAR(); LGKM0(); SCHED0();
    MFMA16(0, 0, bn0); BAR();

    // ---- ph6: T1 m0n1; stage A(2j+3)-q0
    READ_BN(1, 1, bn1);
    if (pf) STG_AQ(1, 0, k3);
    SCHED0(); BAR(); LGKM0(); SCHED0();
    MFMA16(0, 1, bn1); BAR();

    // ---- ph7: T1 m1n0; stage B(2j+3)-n0
    READ_AQ(1, 1);
    if (pf) STG_BN(1, 0, k3);
    SCHED0(); BAR(); LGKM0(); SCHED0();
    MFMA16(1, 0, bn0); BAR();

    // ---- ph8: T1 m1n1; stage B(2j+3)-n1; WAIT (tile 2j+2 ready)
    if (pf) STG_BN(1, 1, k3);
    SCHED0(); BAR(); LGKM0(); SCHED0();
    MFMA16(1, 1, bn1);
    if (pf) {
      asm volatile("s_waitcnt vmcnt(6)" ::: "memory");
      BAR();
    }
  }
#undef STG_AQ
#undef STG_BN
#undef READ_AQ
#undef READ_BN
#undef MFMA16
#undef BAR
#undef SCHED0
#undef LGKM0

  // ---- epilogue
#pragma unroll
  for (int mi = 0; mi < 8; ++mi)
#pragma unroll
    for (int ni = 0; ni < 4; ++ni)
#pragma unroll
      for (int v = 0; v < 4; ++v) {
        int m = bm + wm * 128 + mi * 16 + lg * 4 + v;
        int n = bn + wn * 64 + ni * 16 + lr;
        float val = acc[mi][ni][v];
        if (ROPE) {
          int srow = m & (S_ - 1);
          int j = (n & (HD - 1)) >> 1;
          float c = fc[(size_t)srow * 64 + j];
          float s = fs[(size_t)srow * 64 + j];
          float partner = __shfl_xor(val, 1);
          val = (n & 1) ? (val * c + partner * s) : (val * c - partner * s);
          val *= (0.08838834764831845f * 1.44269504088896340f);  // attn scale (log2)
        }
        if (MODE == 0) {
          ((float*)Cout)[(size_t)m * N + n] = val;
        } else if (MODE == 1) {
          int b = m >> 11, s = m & (S_ - 1), hh = n >> 7, d = n & (HD - 1);
          ((u16*)Cout)[(((size_t)(b * Hh + hh)) * S_ + s) * HD + d] = f2bf(val);
        } else {
          int b = m >> 11, s = m & (S_ - 1), hh = n >> 7, d = n & (HD - 1);
          ((u16*)Cout)[(((size_t)(b * Hh + hh)) * HD + d) * S_ + s] = f2bf(val);
        }
      }
}

// ---------------- merged K+V projection (128^2 2-phase), blockIdx.z selects ----
__global__ __launch_bounds__(256)
void gemm_kv(const u16* __restrict__ Xb, const u16* __restrict__ Wk,
             const u16* __restrict__ Wv, u16* __restrict__ Kr, u16* __restrict__ Vt,
             const float* __restrict__ fc, const float* __restrict__ fs) {
  const int tid = threadIdx.x;
  const int lid = tid & 63, w = tid >> 6;
  const int lr = lid & 15, lg = lid >> 4;
  const int wm = w >> 1, wn = w & 1;
  const int zz = blockIdx.z;
  const u16* Bw = zz ? Wv : Wk;
  const int K = D_;

  const int gx = gridDim.x;
  const int nwg = gx * gridDim.y;
  const int lin = blockIdx.y * gx + blockIdx.x;
  const int cpx = nwg >> 3;
  const int lin2 = (lin & 7) * cpx + (lin >> 3);
  const int bm = (lin2 / gx) * 128, bn = (lin2 % gx) * 128;

  __shared__ __align__(16) u16 Al[128 * 64];
  __shared__ __align__(16) u16 Bl[128 * 64];
  f32x4 acc[4][4];
#pragma unroll
  for (int i = 0; i < 4; ++i)
#pragma unroll
    for (int j = 0; j < 4; ++j) acc[i][j] = (f32x4){0.f, 0.f, 0.f, 0.f};

  for (int k0 = 0; k0 < K; k0 += 64) {
    __syncthreads();
#pragma unroll
    for (int i = 0; i < 4; ++i) {
      int c = i * 256 + tid;
      int row = c >> 3, cb = c & 7;
      int cbs = (cb ^ row) & 7;
      load_lds16(Xb + (size_t)(bm + row) * K + k0 + cbs * 8, &Al[c * 8]);
    }
#pragma unroll
    for (int i = 0; i < 4; ++i) {
      int c = i * 256 + tid;
      int row = c >> 3, cb = c & 7;
      int cbs = (cb ^ row) & 7;
      load_lds16(Bw + (size_t)(bn + row) * K + k0 + cbs * 8, &Bl[c * 8]);
    }
    __syncthreads();
#pragma unroll
    for (int ks = 0; ks < 2; ++ks) {
      short8 af[4], bf[4];
#pragma unroll
      for (int mi = 0; mi < 4; ++mi) {
        int row = wm * 64 + mi * 16 + lr;
        af[mi] = *(const short8*)&Al[row * 64 + (((ks * 4 + lg) ^ row) & 7) * 8];
      }
#pragma unroll
      for (int ni = 0; ni < 4; ++ni) {
        int row = wn * 64 + ni * 16 + lr;
        bf[ni] = *(const short8*)&Bl[row * 64 + (((ks * 4 + lg) ^ row) & 7) * 8];
      }
#pragma unroll
      for (int mi = 0; mi < 4; ++mi)
#pragma unroll
        for (int ni = 0; ni < 4; ++ni)
          acc[mi][ni] = __builtin_amdgcn_mfma_f32_16x16x32_bf16(af[mi], bf[ni], acc[mi][ni], 0, 0, 0);
    }
  }
#pragma unroll
  for (int mi = 0; mi < 4; ++mi)
#pragma unroll
    for (int ni = 0; ni < 4; ++ni)
#pragma unroll
      for (int v = 0; v < 4; ++v) {
        int m = bm + wm * 64 + mi * 16 + lg * 4 + v;
        int n = bn + wn * 64 + ni * 16 + lr;
        float val = acc[mi][ni][v];
        int b = m >> 11, s = m & (S_ - 1), hh = n >> 7, d = n & (HD - 1);
        if (zz == 0) {
          int j = d >> 1;
          float c = fc[(size_t)s * 64 + j];
          float sn = fs[(size_t)s * 64 + j];
          float partner = __shfl_xor(val, 1);
          val = (n & 1) ? (val * c + partner * sn) : (val * c - partner * sn);
          Kr[(((size_t)(b * NKV + hh)) * S_ + s) * HD + d] = f2bf(val);
        } else {
          int x = s & 31;
          int sp = (s & ~31) | (((x >> 2) & 3) * 8 + ((x >> 4) & 1) * 4 + (x & 3));
          Vt[(((size_t)(b * NKV + hh)) * HD + d) * S_ + sp] = f2bf(val);
        }
      }
}

// ---------------- Flash attention, swapped-QK + zero-shuffle PV ----------------
__global__ __launch_bounds__(512, 4)
void attn_k(const u16* __restrict__ Qr, const u16* __restrict__ Kr,
            const u16* __restrict__ Vt, u16* __restrict__ Ao) {
  const int xp = blockIdx.x, h = blockIdx.y, b = blockIdx.z;
  const int kvh = h >> 2;
  const int tid = threadIdx.x, lid = tid & 63, w = tid >> 6;
  const int lr = lid & 15, lg = lid >> 4;
  __shared__ __align__(16) u16 Kl[2][64 * 128];
  __shared__ __align__(16) u16 Vl[2][128 * 64];

  const size_t qbase = ((size_t)(b * NH + h)) * S_ * HD;
  const size_t kbase = ((size_t)(b * NKV + kvh)) * S_ * HD;
  const size_t vbase = ((size_t)(b * NKV + kvh)) * HD * S_;

#define STAGE(BUF, KT)                                                              \
  do {                                                                              \
    _Pragma("unroll")                                                               \
    for (int i_ = 0; i_ < 2; ++i_) {                                                \
      int c_ = i_ * 512 + tid;                                                      \
      int row_ = c_ >> 4, cb_ = c_ & 15;                                            \
      int cbs_ = (cb_ & 8) | ((cb_ ^ row_) & 7);                                    \
      load_lds16(&Kr[kbase + (size_t)((KT) + row_) * HD + cbs_ * 8],                \
                 &Kl[BUF][(i_ * 512 + w * 64) * 8]);                                \
    }                                                                               \
    _Pragma("unroll")                                                               \
    for (int i_ = 0; i_ < 2; ++i_) {                                                \
      int c_ = i_ * 512 + tid;                                                      \
      int d_ = c_ >> 3, cb_ = c_ & 7;                                               \
      int cbs_ = (cb_ ^ d_) & 7;                                                    \
      load_lds16(&Vt[vbase + (size_t)d_ * S_ + (KT) + cbs_ * 8],                    \
                 &Vl[BUF][(i_ * 512 + w * 64) * 8]);                                \
    }                                                                               \
  } while (0)

  for (int part = 0; part < 2; ++part) {
    const int qi = part ? xp : (15 - xp);
    const int qb = qi * 128;
    const int ntiles = qi * 2 + 2;
    const int q_abs = qb + w * 16 + lr;

    short8 qf[4];
#pragma unroll
    for (int ks = 0; ks < 4; ++ks)
      qf[ks] = *(const short8*)&Qr[qbase + (size_t)q_abs * HD + ks * 32 + lg * 8];

    float m2 = -3.0e38f, osum = 0.f;
    f32x4 oacc[8];
#pragma unroll
    for (int nd = 0; nd < 8; ++nd) oacc[nd] = (f32x4){0.f, 0.f, 0.f, 0.f};

    STAGE(0, 0);
    __syncthreads();
    int cur = 0;

    for (int t = 0; t < ntiles; ++t) {
      const int kt = t * 64;
      if (t + 1 < ntiles) STAGE(cur ^ 1, kt + 64);

      f32x4 sc[4];
#pragma unroll
      for (int ni = 0; ni < 4; ++ni) sc[ni] = (f32x4){0.f, 0.f, 0.f, 0.f};
      __builtin_amdgcn_s_setprio(1);
#pragma unroll
      for (int ks = 0; ks < 4; ++ks) {
#pragma unroll
        for (int ni = 0; ni < 4; ++ni) {
          int row = ni * 16 + lr;
          int ch = ks * 4 + lg;
          int chs = (ch & 8) | ((ch ^ row) & 7);
          short8 kf = *(const short8*)&Kl[cur][row * 128 + chs * 8];
          sc[ni] = __builtin_amdgcn_mfma_f32_16x16x32_bf16(kf, qf[ks], sc[ni], 0, 0, 0);
        }
      }
      __builtin_amdgcn_s_setprio(0);

      const bool edge = (kt + 64 > qb);
      if (edge) {
#pragma unroll
        for (int ni = 0; ni < 4; ++ni)
#pragma unroll
          for (int v = 0; v < 4; ++v) {
            int kv = kt + ni * 16 + lg * 4 + v;
            if (kv > q_abs) sc[ni][v] = -3.0e38f;
          }
      }
      float mab = fmaxf(fmaxf(fmaxf(sc[0][0], sc[0][1]), fmaxf(sc[0][2], sc[0][3])),
                        fmaxf(fmaxf(sc[1][0], sc[1][1]), fmaxf(sc[1][2], sc[1][3])));
      float mcd = fmaxf(fmaxf(fmaxf(sc[2][0], sc[2][1]), fmaxf(sc[2][2], sc[2][3])),
                        fmaxf(fmaxf(sc[3][0], sc[3][1]), fmaxf(sc[3][2], sc[3][3])));
      float mx = fmaxf(mab, mcd);
      mx = fmaxf(mx, __shfl_xor(mx, 16));
      mx = fmaxf(mx, __shfl_xor(mx, 32));

      if (__any(mx > m2 + 8.0f)) {
        float mnew = fmaxf(m2, mx);
        float fr = exp2f(m2 - mnew);
        m2 = mnew;
        osum *= fr;
#pragma unroll
        for (int nd = 0; nd < 8; ++nd) oacc[nd] *= fr;
      }

      u32x4 pw0, pw1;
      float ps = 0.f;
#pragma unroll
      for (int ni = 0; ni < 4; ++ni) {
#pragma unroll
        for (int p = 0; p < 2; ++p) {
          float e0 = exp2f(sc[ni][2 * p] - m2);
          float e1 = exp2f(sc[ni][2 * p + 1] - m2);
          ps += e0 + e1;
          u32 pk = cvtpk_bf16(e0, e1);
          if (ni < 2) pw0[(ni & 1) * 2 + p] = pk;
          else        pw1[(ni & 1) * 2 + p] = pk;
        }
      }
      osum += ps;
      const short8 pf0 = u32x4_to_short8(pw0);
      const short8 pf1 = u32x4_to_short8(pw1);

      __builtin_amdgcn_s_setprio(1);
#pragma unroll
      for (int ks = 0; ks < 2; ++ks) {
        const short8 pfk = ks ? pf1 : pf0;
#pragma unroll
        for (int nd = 0; nd < 8; ++nd) {
          int rowv = nd * 16 + lr;
          int ch = ks * 4 + lg;
          short8 vf = *(const short8*)&Vl[cur][rowv * 64 + ((ch ^ rowv) & 7) * 8];
          oacc[nd] = __builtin_amdgcn_mfma_f32_16x16x32_bf16(vf, pfk, oacc[nd], 0, 0, 0);
        }
      }
      __builtin_amdgcn_s_setprio(0);
      __syncthreads();
      cur ^= 1;
    }

    float os = osum;
    os += __shfl_xor(os, 16);
    os += __shfl_xor(os, 32);
    const float inv = 1.0f / os;
    const size_t orow = ((size_t)(b * S_ + q_abs)) * D_ + h * HD;
    u32* AoW = (u32*)Ao;
#pragma unroll
    for (int nd = 0; nd < 8; ++nd) {
#pragma unroll
      for (int p = 0; p < 2; ++p) {
        u32 pk = cvtpk_bf16(oacc[nd][2 * p] * inv, oacc[nd][2 * p + 1] * inv);
        AoW[(orow + nd * 16 + lg * 4 + 2 * p) >> 1] = pk;
      }
    }
  }
#undef STAGE
}

// ---------------- host launch ----------------
extern "C" void kernel_launch(void* const* d_in, const int* in_sizes, int n_in,
                              void* d_out, int out_size, void* d_ws, size_t ws_size,
                              hipStream_t stream) {
  const float* x  = (const float*)d_in[0];
  const float* wq = (const float*)d_in[1];
  const float* wk = (const float*)d_in[2];
  const float* wv = (const float*)d_in[3];
  const float* wo = (const float*)d_in[4];
  const float* fc = (const float*)d_in[5];
  const float* fs = (const float*)d_in[6];

  const size_t SZ_X  = (size_t)B_ * S_ * D_ * 2;
  const size_t SZ_WQ = (size_t)D_ * D_ * 2;
  const size_t SZ_WK = (size_t)NKV * HD * D_ * 2;
  char* ws = (char*)d_ws;
  u16* Xb  = (u16*)(ws);
  u16* Wqb = (u16*)(ws + SZ_X);
  u16* Wkb = (u16*)(ws + SZ_X + SZ_WQ);
  u16* Wvb = (u16*)(ws + SZ_X + SZ_WQ + SZ_WK);
  u16* Wob = (u16*)(ws + SZ_X + SZ_WQ + 2 * SZ_WK);
  u16* Qr  = (u16*)(ws + SZ_X + 2 * SZ_WQ + 2 * SZ_WK);
  u16* Kr  = (u16*)(ws + 2 * SZ_X + 2 * SZ_WQ + 2 * SZ_WK);
  u16* Vt  = (u16*)(ws + 2 * SZ_X + 2 * SZ_WQ + 3 * SZ_WK);
  u16* Ao  = (u16*)(ws + 2 * SZ_X + 2 * SZ_WQ + 4 * SZ_WK);
  const size_t NEEDED = 3 * SZ_X + 2 * SZ_WQ + 4 * SZ_WK;
  if (ws_size < NEEDED) return;

  cvt_all<<<28672, 256, 0, stream>>>(x, wq, wk, wv, wo, Xb, Wqb, Wkb, Wvb, Wob);

  gemm256<1, true><<<dim3(16, 16), 512, 0, stream>>>(
      Xb, Wqb, Qr, B_ * S_, D_, D_, NH, fc, fs);
  gemm_kv<<<dim3(8, 32, 2), 256, 0, stream>>>(Xb, Wkb, Wvb, Kr, Vt, fc, fs);

  attn_k<<<dim3(8, NH, B_), 512, 0, stream>>>(Qr, Kr, Vt, Ao);

  gemm256<0, false><<<dim3(16, 16), 512, 0, stream>>>(
      Ao, Wob, d_out, B_ * S_, D_, D_, 0, nullptr, nullptr);
}